// Round 3
// baseline (357.647 us; speedup 1.0000x reference)
//
#include <hip/hip_runtime.h>
#include <cmath>

#ifndef __has_builtin
#define __has_builtin(x) 0
#endif

#define B_DIM 4096
#define K_DIM 2048
#define N_DIM 2048

#define BM 128
#define BN 128
#define BK 64    // i8: 64 B per row = 4 x 16B chunks; tile buffer 3x8KB = 24 KB

typedef __attribute__((ext_vector_type(4))) float f32x4;
typedef __attribute__((ext_vector_type(4))) int i32x4;
typedef __attribute__((ext_vector_type(16))) signed char i8x16;

// ---------- helpers ----------

__device__ __forceinline__ signed char f2i8(float f) {
    int t = __float2int_rn(f);               // round-half-even, matches rintf/ste_round
    t = t < -127 ? -127 : (t > 127 ? 127 : t);
    return (signed char)t;
}

__device__ __forceinline__ void gl2lds16(const void* g, void* l) {
#if __has_builtin(__builtin_amdgcn_global_load_lds)
    __builtin_amdgcn_global_load_lds((__attribute__((address_space(1))) void*)g,
                                     (__attribute__((address_space(3))) void*)l,
                                     16, 0, 0);
#else
    *(uint4*)l = *(const uint4*)g;
#endif
}

#define VMWAIT0   asm volatile("s_waitcnt vmcnt(0)" ::: "memory")
#define FENCE     asm volatile("" ::: "memory")
#define SBARRIER  do { FENCE; __builtin_amdgcn_s_barrier(); FENCE; } while (0)

// ---------- prep: fp32 -> i8 casts ----------
// X entries are exactly 0.0/1.0; ste_round(W) is integral. i8/i32 GEMM is
// exact (numSyn <= 2048*127 << 2^31), bit-identical to the f32 einsum.

__global__ void cast_x_kernel(const float* __restrict__ X,
                              signed char* __restrict__ Xb) {
    size_t i = ((size_t)blockIdx.x * 256 + threadIdx.x) * 16;
    i8x16 o;
#pragma unroll
    for (int j = 0; j < 16; j += 4) {
        f32x4 a = *(const f32x4*)(X + i + j);
        o[j]     = f2i8(a[0]);
        o[j + 1] = f2i8(a[1]);
        o[j + 2] = f2i8(a[2]);
        o[j + 3] = f2i8(a[3]);
    }
    *(i8x16*)(Xb + i) = o;
}

__global__ void cast_w_kernel(const float* __restrict__ Wa,
                              const float* __restrict__ Ws,
                              signed char* __restrict__ Wab,
                              signed char* __restrict__ Wsb) {
    size_t i = ((size_t)blockIdx.x * 256 + threadIdx.x) * 16;
    i8x16 oa, os;
#pragma unroll
    for (int j = 0; j < 16; j += 4) {
        f32x4 a = *(const f32x4*)(Wa + i + j);
        f32x4 s = *(const f32x4*)(Ws + i + j);
        oa[j]     = f2i8(a[0]); oa[j + 1] = f2i8(a[1]);
        oa[j + 2] = f2i8(a[2]); oa[j + 3] = f2i8(a[3]);
        os[j]     = f2i8(s[0]); os[j + 1] = f2i8(s[1]);
        os[j + 2] = f2i8(s[2]); os[j + 3] = f2i8(s[3]);
    }
    *(i8x16*)(Wab + i) = oa;
    *(i8x16*)(Wsb + i) = os;
}

// ---------- fused dual-GEMM + DPI neuron update ----------
//
// 128x128 tile, 4 waves 2x2 (64x64 wave-tiles), i8 BK=64, mfma_i32_16x16x64.
// 2-PHASE DOUBLE-BUFFERED K-loop (T3 minimum recipe): per tile,
//   ds_reads(buf[t])  ->  DMA stage(t+1 -> buf[t^1])  ->  sched_barrier
//   ->  32 MFMA  ->  vmcnt(0) + s_barrier.
// ds_reads are issued BEFORE the DMA so the backend cannot insert a vmcnt
// wait ahead of them; sched_barrier(0) pins the DMA issue above the MFMA
// cluster so the loads fly under the compute.  Buffer-overwrite hazard: the
// reads of buf[t^1] (tile t-1) retired before tile t-1's end barrier (DS ops
// retire in order; the last MFMA operand wait covers all), and every thread
// passes that barrier before issuing the DMA.  2 x 24 KB buffers in the same
// 48 KB LDS as before -> still 2 blocks/CU for stall absorption + epilogue TLP.
//
// Bank swizzle for 64B rows: read slot = kq ^ ((frow>>1)&3).  Quad-slot of
// (row, slot) = (4*(row&1) + slot) & 7; over a 16-lane group (fixed kq,
// frow 0..15) this covers all 8 quad-slots exactly twice -> 2-way aliasing,
// which is free (m136).  Stage pre-swizzles the GLOBAL source chunk with the
// same XOR so LDS stays linear for global_load_lds (wave-uniform base +
// lane*16).

#define RS 132   // LDS float row stride for epilogue (128 + 4 pad)

__device__ __forceinline__ void stage_tile(int tt, int tid, int m0, int n0,
                                           unsigned char* smem,
                                           const signed char* __restrict__ Xb,
                                           const signed char* __restrict__ Wab,
                                           const signed char* __restrict__ Wsb) {
    unsigned char* bb = smem + (tt & 1) * 24576;
    const int k0s = tt * BK;
    // A: 128 rows x 64 B = 512 chunks; 2 per thread
#pragma unroll
    for (int j = 0; j < 2; j++) {
        const int c   = j * 256 + tid;
        const int row = c >> 2;                    // 4 chunks per row
        const int js  = (c & 3) ^ ((row >> 1) & 3);
        gl2lds16(Xb + (size_t)(m0 + row) * K_DIM + k0s + js * 16, bb + c * 16);
    }
    // Wa / Ws: 512 chunks each; 2+2 per thread
#pragma unroll
    for (int j = 0; j < 2; j++) {
        const int c   = j * 256 + tid;
        const int row = c >> 2;
        const int js  = (c & 3) ^ ((row >> 1) & 3);
        const size_t go = (size_t)(n0 + row) * K_DIM + k0s + js * 16;
        gl2lds16(Wab + go, bb + 8192  + c * 16);
        gl2lds16(Wsb + go, bb + 16384 + c * 16);
    }
}

__global__ __launch_bounds__(256, 2)
void dpi_fused_kernel(const signed char* __restrict__ Xb,
                      const signed char* __restrict__ Wab,
                      const signed char* __restrict__ Wsb,
                      const float* __restrict__ gImem,
                      const float* __restrict__ gIampa,
                      const float* __restrict__ gIshunt,
                      const float* __restrict__ gRefr,
                      const float* __restrict__ pIdc,
                      const float* __restrict__ pIwa,
                      const float* __restrict__ pIws,
                      const float* __restrict__ pAlpha,
                      const float* __restrict__ pBeta,
                      float* __restrict__ out,
                      float i0pow, float kexp, float tau_mem, float inv_tau_syn)
{
    __shared__ __align__(16) unsigned char smem[49152];   // 2 x 24 KB K-loop dbuf
    float* na_buf = (float*)smem;                         // epilogue reuse: 16896 B
    float* ns_buf = (float*)(smem + 16896);               // 16896 B

    const int tid  = threadIdx.x;
    const int lane = tid & 63;
    const int wave = tid >> 6;

    // XCD-aware swizzle: 8 XCDs, each gets an 8x8 block region (1024x1024 elems)
    const int lin = blockIdx.x;                 // 0..511
    const int xcd = lin & 7;
    const int loc = lin >> 3;                   // 0..63
    const int mb  = (xcd & 3) * 8 + (loc & 7);  // 0..31
    const int nb  = (xcd >> 2) * 8 + (loc >> 3);// 0..15
    const int m0  = mb * BM;
    const int n0  = nb * BN;

    const int wm = (wave & 1) * 64;
    const int wn = (wave >> 1) * 64;

    i32x4 accA[4][4], accS[4][4];
#pragma unroll
    for (int i = 0; i < 4; i++)
#pragma unroll
        for (int j = 0; j < 4; j++) { accA[i][j] = (i32x4)0; accS[i][j] = (i32x4)0; }

    const int frow   = lane & 15;                       // m (or n) within a 16-frag
    const int kq     = lane >> 4;                       // k sub-chunk 0..3
    const int slot16 = (kq ^ ((frow >> 1) & 3)) * 16;   // swizzled 16B slot (per-lane const;
                                                        // (row>>1)&3 == (frow>>1)&3 since
                                                        // row = 16q + frow and 8q % 4 == 0)

    // prologue: tile 0 into buf0
    stage_tile(0, tid, m0, n0, smem, Xb, Wab, Wsb);
    VMWAIT0; SBARRIER;

#pragma unroll 2
    for (int t = 0; t < 32; ++t) {
        const unsigned char* bb = smem + (t & 1) * 24576;
        const signed char* sA  = (const signed char*)bb;
        const signed char* sWa = (const signed char*)(bb + 8192);
        const signed char* sWs = (const signed char*)(bb + 16384);

        // 1) operand reads first (no DMA outstanding -> no vmcnt stall possible)
        i32x4 af[4], ba[4], bs[4];
#pragma unroll
        for (int mi = 0; mi < 4; mi++)
            af[mi] = *(const i32x4*)(sA + (wm + mi * 16 + frow) * 64 + slot16);
#pragma unroll
        for (int ni = 0; ni < 4; ni++) {
            const int o = (wn + ni * 16 + frow) * 64 + slot16;
            ba[ni] = *(const i32x4*)(sWa + o);
            bs[ni] = *(const i32x4*)(sWs + o);
        }

        // 2) issue next tile's DMA into the other buffer (flies under MFMA)
        if (t < 31) stage_tile(t + 1, tid, m0, n0, smem, Xb, Wab, Wsb);
        __builtin_amdgcn_sched_barrier(0);   // pin DMA issue above the MFMA cluster

        // 3) compute (compiler inserts fine-grained lgkmcnt before operand use)
#pragma unroll
        for (int mi = 0; mi < 4; mi++)
#pragma unroll
            for (int ni = 0; ni < 4; ni++) {
                accA[mi][ni] = __builtin_amdgcn_mfma_i32_16x16x64_i8(af[mi], ba[ni], accA[mi][ni], 0, 0, 0);
                accS[mi][ni] = __builtin_amdgcn_mfma_i32_16x16x64_i8(af[mi], bs[ni], accS[mi][ni], 0, 0, 0);
            }

        // 4) the tile's only drain: next-tile data landed + all waves done reading
        VMWAIT0; SBARRIER;
    }

    // ---- epilogue: transpose through LDS, then contiguous float4 I/O ----
    const float idc   = *pIdc;
    const float iwa   = *pIwa;
    const float iws   = *pIws;
    const float alpha = *pAlpha;
    const float beta  = *pBeta;

    const size_t plane = (size_t)B_DIM * N_DIM;
    float* __restrict__ oSpike = out;
    float* __restrict__ oImem  = out + plane;
    float* __restrict__ oIampa = out + 2 * plane;
    float* __restrict__ oIsh   = out + 3 * plane;
    float* __restrict__ oRefr  = out + 4 * plane;

    const int rowgroup = wm >> 6;          // 0 or 1
    const int quad4    = (lane >> 4) << 2; // 0,4,8,12
    const int cseg     = (tid & 31) * 4;   // float4 column
    const int rgrp     = tid >> 5;         // 0..7 -> rows rgrp*4..+3

#pragma unroll
    for (int s = 0; s < 4; s++) {          // s == mi: 32 rows of the tile per step
        // scatter fragments into LDS (C/D layout: col=lane&15, row=quad*4+r;
        // dtype-independent, so identical for i8 -> i32 acc)
#pragma unroll
        for (int ni = 0; ni < 4; ni++) {
            const int lcol = wn + ni * 16 + (lane & 15);
#pragma unroll
            for (int r = 0; r < 4; r++) {
                const int lrow = rowgroup * 16 + quad4 + r;
                na_buf[lrow * RS + lcol] = (float)accA[s][ni][r];
                ns_buf[lrow * RS + lcol] = (float)accS[s][ni][r];
            }
        }
        __syncthreads();

        // contiguous compute + store: each thread owns 4 rows x 1 float4
#pragma unroll
        for (int q = 0; q < 4; q++) {
            const int lrow = rgrp * 4 + q;
            const int grow = m0 + (lrow >> 4) * 64 + s * 16 + (lrow & 15);
            const size_t idx = (size_t)grow * N_DIM + n0 + cseg;

            const f32x4 na4 = *(const f32x4*)(na_buf + lrow * RS + cseg);
            const f32x4 ns4 = *(const f32x4*)(ns_buf + lrow * RS + cseg);
            const f32x4 im4 = *(const f32x4*)(gImem   + idx);
            const f32x4 ia4 = *(const f32x4*)(gIampa  + idx);
            const f32x4 is4 = *(const f32x4*)(gIshunt + idx);
            const f32x4 rf4 = *(const f32x4*)(gRefr   + idx);

            f32x4 sp_o, im_o, ia_o, is_o, rf_o;
#pragma unroll
            for (int e = 0; e < 4; e++) {
                const float na  = na4[e];
                const float ns  = ns4[e];
                const float im  = im4[e];
                const float ia  = ia4[e];
                const float ish = is4[e];
                const float rf  = rf4[e];

                const float dIampa  = -ia * inv_tau_syn;
                const float ia2     = ia + iwa * na;        // IGAIN_AMPA/ITAU_AMPA = 1
                const float dIshunt = -ish * inv_tau_syn;   // TAU_SHUNT == TAU_AMPA
                const float ish2    = ish + iws * ns;

                float Iin = idc + ia2 + 5e-13f - ish2;      // Inmda = I0
                Iin = (rf <= 0.0f) ? Iin : 0.0f;
                Iin = fmaxf(Iin, 5e-13f);

                // 1+exp(-1e-12*(im-1e-12)): |arg| < 1e-21 -> exp == 1.0f exactly
                // in fp32, denominator == 2.0f. powf via v_log/v_exp.
                const float ifb = i0pow *
                    __builtin_amdgcn_exp2f(kexp * __builtin_amdgcn_logf(im)) * 0.5f;
                const float fimem = ifb * 1e12f * (im + 1e-12f);
                const float dImem = (alpha * ((Iin - 1e-12f) - 5e-13f) - beta * im + fimem)
                                    / (tau_mem * (1.0f + 1e-12f / im));
                float im2 = fmaxf(im + dImem * 0.001f, 5e-13f);

                float ia3 = fmaxf(ia2 + dIampa * 0.001f, 5e-13f);
                ia3       = fmaxf(ia3 + dIshunt * 0.001f, 5e-13f);  // faithful to ref bug

                const float spike = (im2 - 1e-12f > 0.0f) ? 1.0f : 0.0f;
                im2 = (spike > 0.0f) ? 5e-13f : im2;
                float rf2 = fmaxf(rf - 0.001f, 0.0f);
                rf2 = (spike > 0.0f) ? 0.0f : rf2;          // REFP = 0

                sp_o[e] = spike; im_o[e] = im2; ia_o[e] = ia3;
                is_o[e] = ish2;  rf_o[e] = rf2;
            }

            *(f32x4*)(oSpike + idx) = sp_o;
            *(f32x4*)(oImem  + idx) = im_o;
            *(f32x4*)(oIampa + idx) = ia_o;
            *(f32x4*)(oIsh   + idx) = is_o;
            *(f32x4*)(oRefr  + idx) = rf_o;
        }
        __syncthreads();
    }
}

// ---------- launch ----------

extern "C" void kernel_launch(void* const* d_in, const int* in_sizes, int n_in,
                              void* d_out, int out_size, void* d_ws, size_t ws_size,
                              hipStream_t stream) {
    (void)in_sizes; (void)n_in; (void)out_size; (void)ws_size;

    const float* X       = (const float*)d_in[0];
    const float* W_ampa  = (const float*)d_in[1];
    const float* W_shunt = (const float*)d_in[2];
    const float* Imem    = (const float*)d_in[3];
    const float* Iampa   = (const float*)d_in[4];
    const float* Ishunt  = (const float*)d_in[5];
    const float* Refr    = (const float*)d_in[6];
    const float* pIdc    = (const float*)d_in[7];
    const float* pIwa    = (const float*)d_in[8];
    const float* pIws    = (const float*)d_in[9];
    const float* pAlpha  = (const float*)d_in[10];
    const float* pBeta   = (const float*)d_in[11];

    signed char* Xb  = (signed char*)d_ws;                 // 8 MiB
    signed char* Wab = Xb  + (size_t)B_DIM * K_DIM;        // 4 MiB
    signed char* Wsb = Wab + (size_t)N_DIM * K_DIM;        // 4 MiB

    const float i0pow       = (float)std::pow(5e-13, 1.0 / 1.705);   // I0^(1/(k+1))
    const float kexp        = (float)(0.705 / 1.705);                // k/(k+1)
    const float tau_mem     = (float)(0.025 / 0.705 * 3.0);
    const float inv_tau_syn = (float)(1.0 / (0.025 / 0.705 * 2.0));

    cast_x_kernel<<<dim3((B_DIM * K_DIM) / (256 * 16)), dim3(256), 0, stream>>>(X, Xb);
    cast_w_kernel<<<dim3((N_DIM * K_DIM) / (256 * 16)), dim3(256), 0, stream>>>(
        W_ampa, W_shunt, Wab, Wsb);

    dpi_fused_kernel<<<dim3(512), dim3(256), 0, stream>>>(
        Xb, Wab, Wsb, Imem, Iampa, Ishunt, Refr,
        pIdc, pIwa, pIws, pAlpha, pBeta,
        (float*)d_out, i0pow, kexp, tau_mem, inv_tau_syn);
}